// Round 15
// baseline (521.095 us; speedup 1.0000x reference)
//
#include <hip/hip_runtime.h>
#include <cstdint>
#include <cstddef>

#define RFL(x) __builtin_amdgcn_readfirstlane(x)

constexpr int E  = 64;     // channels in SS2D stage
constexpr int Rr = 32;     // low rank
constexpr int Nn = 64;     // state dim
constexpr int Lt = 3136;   // 56*56 tokens
constexpr int NC = 28;     // scan chunks
constexpr int CL = 112;    // Lt/NC
constexpr int PD = 192;    // packed proj row: [u(32) | dt(32) | B(64) | C(64)]

// ---------------- SS2D weight transpose: wT[i][c][o] ----------------
__global__ __launch_bounds__(256) void k_wtrans(const float* __restrict__ in_w,
    const float* __restrict__ dt_w, const float* __restrict__ B_w,
    const float* __restrict__ C_w, float* __restrict__ wT) {
  int idx = blockIdx.x * 256 + threadIdx.x;
  if (idx >= 3 * 64 * PD) return;
  int o = idx % PD; int c = (idx / PD) & 63; int i = idx / (PD * 64);
  float v;
  if (o < 32)       v = in_w[(i * 32 + o) * 64 + c];
  else if (o < 64)  v = dt_w[(i * 32 + (o - 32)) * 64 + c];
  else if (o < 128) v = B_w[(i * 64 + (o - 64)) * 64 + c];
  else              v = C_w[(i * 64 + (o - 128)) * 64 + c];
  wT[idx] = v;
}

// ---------------- conv3x3 s2 p1 + BN + SiLU: spatial-lane, scalar weights ----------------
// lane = (oh_sub, ow); co is wave-uniform (CO_TILE loop) -> weight loads go through
// the scalar/SMEM pipe; x taps are per-lane stride-2 global loads (L1/L2-served).
// No LDS, no barriers.
template<int CIN, int COUT, int HIN, int WIN, int RPW, int COT>
__global__ __launch_bounds__(256) void k_conv5(const float* __restrict__ x,
    const float* __restrict__ w, const float* __restrict__ g, const float* __restrict__ bb,
    const float* __restrict__ m, const float* __restrict__ vv, float* __restrict__ out) {
  constexpr int HOUT = HIN / 2, WOUT = WIN / 2;
  constexpr int RPB = 4 * RPW;                    // rows per block (4 waves)
  constexpr int OHG = (HOUT + RPB - 1) / RPB;
  int t = blockIdx.x;
  int b = t & 7; t >>= 3;
  int ohg = t % OHG; int cog = t / OHG;
  int wave = threadIdx.x >> 6, lane = threadIdx.x & 63;
  if (lane >= RPW * WOUT) return;                 // no barriers -> early exit OK
  int ohs = lane / WOUT, ow = lane - ohs * WOUT;
  int oh = ohg * RPB + wave * RPW + ohs;
  if (oh >= HOUT) return;
  int co0 = cog * COT;
  const float* xb = x + (size_t)b * CIN * HIN * WIN;
  int ih0 = oh * 2 - 1;
  int iw = ow * 2;
  float acc[COT];
#pragma unroll
  for (int j = 0; j < COT; ++j) acc[j] = 0.f;
#pragma unroll 2
  for (int ci = 0; ci < CIN; ++ci) {
    const float* xp = xb + (size_t)ci * HIN * WIN;
    float tp[3][3];
#pragma unroll
    for (int kh = 0; kh < 3; ++kh) {
      int ih = ih0 + kh;
      bool rok = (unsigned)ih < (unsigned)HIN;
      const float* xr = xp + (size_t)ih * WIN;
      tp[kh][0] = (rok && ow > 0) ? xr[iw - 1] : 0.f;
      tp[kh][1] = rok ? xr[iw] : 0.f;
      tp[kh][2] = rok ? xr[iw + 1] : 0.f;
    }
    const float* wc = w + (size_t)(co0 * CIN + ci) * 9;   // wave-uniform -> s_load
#pragma unroll
    for (int j = 0; j < COT; ++j) {
      const float* wj = wc + (size_t)j * CIN * 9;
#pragma unroll
      for (int k = 0; k < 9; ++k)
        acc[j] = fmaf(tp[k / 3][k % 3], wj[k], acc[j]);
    }
  }
#pragma unroll
  for (int j = 0; j < COT; ++j) {
    int c2 = co0 + j;
    float scale = g[c2] * rsqrtf(vv[c2] + 1e-5f);
    float yv = (acc[j] - m[c2]) * scale + bb[c2];
    out[(((size_t)(b * COUT + c2)) * HOUT + oh) * WOUT + ow] =
        yv / (1.f + __expf(-yv));
  }
}

// ---------------- token projections: x[b][c][l] -> P[b][l][192], LDS-staged stores ----------------
__global__ __launch_bounds__(256) void k_proj(const float* __restrict__ xin,
    const float* __restrict__ wT, const float* __restrict__ dt_b, float* __restrict__ P) {
  __shared__ float sm[64 * 196];          // phase A: xl[64][65]; phase B: out[64 tok][196 pad]
  int b = blockIdx.x & 7, tl = blockIdx.x >> 3;
  int l0 = tl * 64;
  int tid = threadIdx.x;
  for (int k = 0; k < 16; ++k) {
    int idx = k * 256 + tid; int c = idx >> 6, li = idx & 63;
    sm[c * 65 + li] = xin[(size_t)(b * 64 + c) * Lt + l0 + li];
  }
  __syncthreads();
  int tok = tid & 63;
  int og = RFL(tid >> 6);
  const float* wbase = wT + og * 48;
  float acc[48];
#pragma unroll
  for (int j = 0; j < 48; ++j) acc[j] = 0.f;
  for (int c = 0; c < 64; ++c) {
    float xv = sm[c * 65 + tok];
    const float4* w4 = (const float4*)(wbase + c * PD);
#pragma unroll
    for (int j = 0; j < 12; ++j) {
      float4 wv = __ldg(w4 + j);
      acc[4 * j + 0] = fmaf(xv, wv.x, acc[4 * j + 0]);
      acc[4 * j + 1] = fmaf(xv, wv.y, acc[4 * j + 1]);
      acc[4 * j + 2] = fmaf(xv, wv.z, acc[4 * j + 2]);
      acc[4 * j + 3] = fmaf(xv, wv.w, acc[4 * j + 3]);
    }
  }
  __syncthreads();                         // xl dead; reuse sm for output staging
#pragma unroll
  for (int j = 0; j < 48; ++j) {
    int o = og * 48 + j;
    float v = acc[j];
    if (o >= 32 && o < 64) {
      v += dt_b[o - 32];
      v = fmaxf(v, 0.f) + log1pf(__expf(-fabsf(v)));   // softplus
    }
    sm[tok * 196 + o] = v;
  }
  __syncthreads();
  float* dst = P + ((size_t)(b * Lt + l0)) * PD;       // 12288 contiguous floats
#pragma unroll
  for (int it = 0; it < 12; ++it) {
    int f = it * 1024 + tid * 4;
    int tk = f / 192;
    float4 v = *(const float4*)(&sm[tk * 196 + (f - tk * 192)]);
    *(float4*)(dst + f) = v;
  }
}

// ---------------- scan phase 1: per-chunk local scan summary (P LDS-staged) ----------------
__global__ __launch_bounds__(256) void k_scan1(const float* __restrict__ P,
    const float* __restrict__ A_log, float* __restrict__ hfin, float* __restrict__ Pc) {
  __shared__ float xl[16][132];
  int bid = blockIdx.x;
  int b = bid & 7; int rest = bid >> 3;
  int c = rest % NC; int rg = rest / NC;      // rg 0..7
  int ws = RFL(threadIdx.x >> 6);
  int r = rg * 4 + ws;
  int n = threadIdx.x & 63;
  float a = -__expf(A_log[r * 64 + n]);
  const float* base = P + ((size_t)(b * Lt + c * CL)) * PD;
  int tl = threadIdx.x >> 4;                  // 0..15
  int colb = (threadIdx.x & 15) * 8;          // 0..120
  float h = 0.f, sdt = 0.f;
  for (int s0 = 0; s0 < CL; s0 += 16) {
    __syncthreads();
    const float4* src = (const float4*)(base + (size_t)(s0 + tl) * PD + colb);
    float4 v0 = src[0], v1 = src[1];
    *(float4*)(&xl[tl][colb]) = v0;
    *(float4*)(&xl[tl][colb + 4]) = v1;
    __syncthreads();
#pragma unroll
    for (int tt = 0; tt < 16; ++tt) {
      float dt = xl[tt][32 + r];
      float u  = xl[tt][r];
      float bt = xl[tt][64 + n];
      h = fmaf(__expf(dt * a), h, (dt * u) * bt);
      sdt += dt;
    }
  }
  int o = ((b * 32 + r) * NC + c) * 64 + n;
  hfin[o] = h;
  Pc[o] = __expf(a * sdt);
}

// ---------------- scan phase 3: inline chunk-prefix + emit states (nontemporal) + y ----------------
__global__ __launch_bounds__(256) void k_scan3(const float* __restrict__ P,
    const float* __restrict__ A_log, const float* __restrict__ hfin,
    const float* __restrict__ Pcp, const float* __restrict__ Dp,
    float* __restrict__ states, float* __restrict__ y) {
  __shared__ float xl[16][196];
  __shared__ __align__(16) float ylds[4][16][68];
  int bid = blockIdx.x;
  int b = bid & 7; int rest = bid >> 3;
  int c = rest % NC; int rg = rest / NC;
  int ws = RFL(threadIdx.x >> 6);
  int r = rg * 4 + ws;
  int n = threadIdx.x & 63;
  float a = -__expf(A_log[r * 64 + n]);
  float Dr = Dp[r];
  const float* base = P + ((size_t)(b * Lt + c * CL)) * PD;
  // inline scan2: prefix over chunks < c
  float h = 0.f;
  {
    int bp = ((b * 32 + r) * NC) * 64 + n;
    for (int cc = 0; cc < c; ++cc)
      h = fmaf(Pcp[bp + cc * 64], h, hfin[bp + cc * 64]);
  }
  float* st = states + ((size_t)(b * Lt + c * CL) * 32 + r) * 64 + n;
  float* yrow = y + (size_t)(b * 32 + r) * Lt + c * CL;
  int tl = threadIdx.x >> 4;
  int colb = (threadIdx.x & 15) * 12;         // 0..180
  for (int s0 = 0; s0 < CL; s0 += 16) {
    __syncthreads();
    const float4* src = (const float4*)(base + (size_t)(s0 + tl) * PD + colb);
    float4 v0 = src[0], v1 = src[1], v2 = src[2];
    *(float4*)(&xl[tl][colb])     = v0;
    *(float4*)(&xl[tl][colb + 4]) = v1;
    *(float4*)(&xl[tl][colb + 8]) = v2;
    __syncthreads();
#pragma unroll
    for (int tt = 0; tt < 16; ++tt) {
      float dt = xl[tt][32 + r];
      float u  = xl[tt][r];
      float bt = xl[tt][64 + n];
      float ct = xl[tt][128 + n];
      h = fmaf(__expf(dt * a), h, (dt * u) * bt);
      __builtin_nontemporal_store(h, st + (size_t)(s0 + tt) * 2048);
      ylds[ws][tt][n] = h * ct;
    }
    if (n < 16) {
      const float4* rp = (const float4*)(&ylds[ws][n][0]);
      float a0 = 0.f, a1 = 0.f, a2 = 0.f, a3 = 0.f;
#pragma unroll
      for (int k = 0; k < 16; ++k) {
        float4 pv = rp[k];
        a0 += pv.x; a1 += pv.y; a2 += pv.z; a3 += pv.w;
      }
      float sum = (a0 + a1) + (a2 + a3);
      float uu = xl[n][r];
      yrow[s0 + n] = sum + Dr * uu;
    }
  }
}

// ---------------- out projection + residual ----------------
__global__ __launch_bounds__(256) void k_outproj(const float* __restrict__ xin,
    const float* __restrict__ y, const float* __restrict__ ow, float* __restrict__ xout) {
  __shared__ float ylds[32 * 64];
  int b = blockIdx.x & 7, tl = blockIdx.x >> 3;
  int l0 = tl * 64;
  int tid = threadIdx.x;
  for (int k = 0; k < 8; ++k) {
    int idx = k * 256 + tid; int r = idx >> 6, li = idx & 63;
    ylds[r * 64 + li] = y[(size_t)(b * 32 + r) * Lt + l0 + li];
  }
  __syncthreads();
  int li = tid & 63, cg = RFL(tid >> 6);
  for (int cc = 0; cc < 16; ++cc) {
    int ci = cg * 16 + cc;
    float acc = xin[(size_t)(b * 64 + ci) * Lt + l0 + li];
    const float4* w4 = (const float4*)(ow + ci * 32);
#pragma unroll
    for (int r4 = 0; r4 < 8; ++r4) {
      float4 wv = __ldg(w4 + r4);
      acc = fmaf(ylds[(r4 * 4 + 0) * 64 + li], wv.x, acc);
      acc = fmaf(ylds[(r4 * 4 + 1) * 64 + li], wv.y, acc);
      acc = fmaf(ylds[(r4 * 4 + 2) * 64 + li], wv.z, acc);
      acc = fmaf(ylds[(r4 * 4 + 3) * 64 + li], wv.w, acc);
    }
    xout[(size_t)(b * 64 + ci) * Lt + l0 + li] = acc;
  }
}

extern "C" void kernel_launch(void* const* d_in, const int* in_sizes, int n_in,
                              void* d_out, int out_size, void* d_ws, size_t ws_size,
                              hipStream_t stream) {
  const float* x      = (const float*)d_in[0];
  const float* stem_w = (const float*)d_in[1];
  const float* stem_g = (const float*)d_in[2];
  const float* stem_b = (const float*)d_in[3];
  const float* stem_m = (const float*)d_in[4];
  const float* stem_v = (const float*)d_in[5];
  const float* in_w   = (const float*)d_in[6];
  const float* dt_w   = (const float*)d_in[7];
  const float* dt_b   = (const float*)d_in[8];
  const float* B_w    = (const float*)d_in[9];
  const float* C_w    = (const float*)d_in[10];
  const float* A_log  = (const float*)d_in[11];
  const float* Dp     = (const float*)d_in[12];
  const float* out_w  = (const float*)d_in[13];
  const float* p4_w   = (const float*)d_in[14];
  const float* p4_g   = (const float*)d_in[15];
  const float* p4_b   = (const float*)d_in[16];
  const float* p4_m   = (const float*)d_in[17];
  const float* p4_v   = (const float*)d_in[18];
  const float* p5_w   = (const float*)d_in[19];
  const float* p5_g   = (const float*)d_in[20];
  const float* p5_b   = (const float*)d_in[21];
  const float* p5_m   = (const float*)d_in[22];
  const float* p5_v   = (const float*)d_in[23];

  float* out = (float*)d_out;
  float* wsf = (float*)d_ws;

  // output regions
  float* p3out = out;                       // 8*64*56*56  = 1605632
  float* p4out = out + 1605632;             // 8*128*28*28 =  802816
  float* p5out = out + 2408448;             // 8*256*14*14 =  401408
  float* stout = out + 2809856;             // 3*8*3136*32*64

  // workspace layout (floats) ~39 MB
  float* x0    = wsf;                   // 1605632
  float* x1    = wsf + 1605632;         // 1605632
  float* Pb    = wsf + 3211264;         // 4816896 (8*3136*192)
  float* yb    = wsf + 8028160;         //  802816 (8*32*3136)
  float* hfin  = wsf + 8830976;         //  458752 (8*32*28*64)
  float* Pc    = wsf + 9289728;         //  458752
  float* wT    = wsf + 9748480;         //   36864 (3*64*192)

  k_wtrans<<<144, 256, 0, stream>>>(in_w, dt_w, B_w, C_w, wT);

  // stem: [8,32,112,112] -> [8,64,56,56]; RPW=1 (4 rows/blk), OHG=14, COT=8 -> 896 blocks
  k_conv5<32, 64, 112, 112, 1, 8><<<896, 256, 0, stream>>>(
      x, stem_w, stem_g, stem_b, stem_m, stem_v, x0);

  const float* xi = x0;
  for (int i = 0; i < 3; ++i) {
    k_proj<<<392, 256, 0, stream>>>(xi, wT + i * 64 * PD, dt_b + i * 32, Pb);
    k_scan1<<<1792, 256, 0, stream>>>(Pb, A_log + i * 2048, hfin, Pc);
    k_scan3<<<1792, 256, 0, stream>>>(Pb, A_log + i * 2048, hfin, Pc, Dp + i * 32,
                                      stout + (size_t)i * 51380224, yb);
    float* dst = (i == 2) ? p3out : ((i == 0) ? x1 : x0);
    k_outproj<<<392, 256, 0, stream>>>(xi, yb, out_w + i * 2048, dst);
    xi = dst;
  }

  // p4: [8,64,56,56] -> [8,128,28,28]; RPW=2 (8 rows/blk), OHG=4, COT=8 -> 512 blocks
  k_conv5<64, 128, 56, 56, 2, 8><<<512, 256, 0, stream>>>(
      p3out, p4_w, p4_g, p4_b, p4_m, p4_v, p4out);
  // p5: [8,128,28,28] -> [8,256,14,14]; RPW=4 (16 rows/blk), OHG=1, COT=8 -> 256 blocks
  k_conv5<128, 256, 28, 28, 4, 8><<<256, 256, 0, stream>>>(
      p4out, p5_w, p5_g, p5_b, p5_m, p5_v, p5out);
}

// Round 16
// 404.948 us; speedup vs baseline: 1.2868x; 1.2868x over previous
//
#include <hip/hip_runtime.h>
#include <cstdint>
#include <cstddef>

#define RFL(x) __builtin_amdgcn_readfirstlane(x)

constexpr int E  = 64;     // channels in SS2D stage
constexpr int Rr = 32;     // low rank
constexpr int Nn = 64;     // state dim
constexpr int Lt = 3136;   // 56*56 tokens
constexpr int NC = 28;     // scan chunks
constexpr int CL = 112;    // Lt/NC
constexpr int PD = 192;    // packed proj row: [u(32) | dt(32) | B(64) | C(64)]

// ---------------- merged setup: SS2D weight transpose + 3 conv weight repacks ----------------
__global__ __launch_bounds__(256) void k_setup(
    const float* __restrict__ in_w, const float* __restrict__ dt_w,
    const float* __restrict__ B_w, const float* __restrict__ C_w,
    const float* __restrict__ stem_w, const float* __restrict__ p4_w,
    const float* __restrict__ p5_w,
    float* __restrict__ wT, float* __restrict__ w3s,
    float* __restrict__ w34, float* __restrict__ w35) {
  int idx = blockIdx.x * 256 + threadIdx.x;
  if (idx < 36864) {
    int o = idx % PD; int c = (idx / PD) & 63; int i = idx / (PD * 64);
    float v;
    if (o < 32)       v = in_w[(i * 32 + o) * 64 + c];
    else if (o < 64)  v = dt_w[(i * 32 + (o - 32)) * 64 + c];
    else if (o < 128) v = B_w[(i * 64 + (o - 64)) * 64 + c];
    else              v = C_w[(i * 64 + (o - 128)) * 64 + c];
    wT[idx] = v;
  } else if (idx < 36864 + 18432) {
    int j = idx - 36864;
    int co = j % 64; int k = (j / 64) % 9; int ci = j / (64 * 9);
    w3s[j] = stem_w[((size_t)co * 32 + ci) * 9 + k];
  } else if (idx < 36864 + 18432 + 73728) {
    int j = idx - 36864 - 18432;
    int co = j % 128; int k = (j / 128) % 9; int ci = j / (128 * 9);
    w34[j] = p4_w[((size_t)co * 64 + ci) * 9 + k];
  } else if (idx < 36864 + 18432 + 73728 + 294912) {
    int j = idx - 36864 - 18432 - 73728;
    int co = j % 256; int k = (j / 256) % 9; int ci = j / (256 * 9);
    w35[j] = p5_w[((size_t)co * 128 + ci) * 9 + k];
  }
}

// ---------------- conv3x3 s2 p1 + BN + SiLU: wave-ci-split, uniform-global taps ----------------
// lane = co (64 per cog); 4 waves own CIN/4 input channels each (partial acc, LDS reduce).
// x taps are WAVE-UNIFORM global scalar loads (scalar-cache path, no LDS staging, no
// x-barrier); weights [ci][9][co] -> coalesced 256B per-lane loads.
template<int CIN, int COUT, int HIN, int WIN>
__global__ __launch_bounds__(256) void k_conv6(const float* __restrict__ x,
    const float* __restrict__ w3, const float* __restrict__ g, const float* __restrict__ bb,
    const float* __restrict__ m, const float* __restrict__ vv, float* __restrict__ out) {
  constexpr int HOUT = HIN / 2, WOUT = WIN / 2;
  constexpr int OWT = 7;
  constexpr int GWX = WOUT / OWT;          // exact for 56/28/14
  constexpr int CIW = CIN / 4;             // ci per wave
  __shared__ float tbuf[4][64][8];

  int t = blockIdx.x;
  int b = t & 7; t >>= 3;
  int oh = t % HOUT; t /= HOUT;
  int gx = t % GWX; int cog = t / GWX;
  int lane = threadIdx.x & 63;
  int ws = RFL(threadIdx.x >> 6);          // wave 0..3 = ci slice (uniform)
  int co = cog * 64 + lane;
  int iwb = gx * 14;                       // taps span iw = iwb-1 .. iwb+13
  int ih0 = oh * 2 - 1;
  bool leftok = (iwb > 0);                 // block-uniform

  const float* xb = x + (size_t)b * CIN * HIN * WIN;
  float acc[OWT];
#pragma unroll
  for (int o = 0; o < OWT; ++o) acc[o] = 0.f;

  int ci0 = ws * CIW;
#pragma unroll 2
  for (int cc = 0; cc < CIW; ++cc) {
    int ci = ci0 + cc;
    const float* xp = xb + (size_t)ci * HIN * WIN;
    const float* wr = w3 + ((size_t)(ci * 9)) * COUT + co;
    float wk[9];
#pragma unroll
    for (int k = 0; k < 9; ++k) wk[k] = wr[(size_t)k * COUT];
#pragma unroll
    for (int kh = 0; kh < 3; ++kh) {
      int ih = ih0 + kh;                   // ih < HIN always (stride-2, pad-1, even HIN)
      if (ih >= 0) {                       // block-uniform branch (only oh==0,kh==0 skips)
        const float* xr = xp + (size_t)ih * WIN + iwb;   // wave-uniform address
        float tp[15];
        tp[0] = leftok ? xr[-1] : 0.f;
#pragma unroll
        for (int j = 1; j < 15; ++j) tp[j] = xr[j - 1];
#pragma unroll
        for (int o = 0; o < OWT; ++o) {
          acc[o] = fmaf(tp[2 * o],     wk[kh * 3 + 0], acc[o]);
          acc[o] = fmaf(tp[2 * o + 1], wk[kh * 3 + 1], acc[o]);
          acc[o] = fmaf(tp[2 * o + 2], wk[kh * 3 + 2], acc[o]);
        }
      }
    }
  }
#pragma unroll
  for (int o = 0; o < OWT; ++o) tbuf[ws][lane][o] = acc[o];
  __syncthreads();

  for (int i = threadIdx.x; i < 64 * OWT; i += 256) {
    int cl = i / OWT, o = i - cl * OWT;
    float s = tbuf[0][cl][o] + tbuf[1][cl][o] + tbuf[2][cl][o] + tbuf[3][cl][o];
    int c2 = cog * 64 + cl;
    float scale = g[c2] * rsqrtf(vv[c2] + 1e-5f);
    float yv = (s - m[c2]) * scale + bb[c2];
    out[(((size_t)(b * COUT + c2)) * HOUT + oh) * WOUT + gx * OWT + o] =
        yv / (1.f + __expf(-yv));
  }
}

// ---------------- token projections: x[b][c][l] -> P[b][l][192], LDS-staged stores ----------------
__global__ __launch_bounds__(256) void k_proj(const float* __restrict__ xin,
    const float* __restrict__ wT, const float* __restrict__ dt_b, float* __restrict__ P) {
  __shared__ float sm[64 * 196];          // phase A: xl[64][65]; phase B: out[64 tok][196 pad]
  int b = blockIdx.x & 7, tl = blockIdx.x >> 3;
  int l0 = tl * 64;
  int tid = threadIdx.x;
  for (int k = 0; k < 16; ++k) {
    int idx = k * 256 + tid; int c = idx >> 6, li = idx & 63;
    sm[c * 65 + li] = xin[(size_t)(b * 64 + c) * Lt + l0 + li];
  }
  __syncthreads();
  int tok = tid & 63;
  int og = RFL(tid >> 6);
  const float* wbase = wT + og * 48;
  float acc[48];
#pragma unroll
  for (int j = 0; j < 48; ++j) acc[j] = 0.f;
  for (int c = 0; c < 64; ++c) {
    float xv = sm[c * 65 + tok];
    const float4* w4 = (const float4*)(wbase + c * PD);
#pragma unroll
    for (int j = 0; j < 12; ++j) {
      float4 wv = __ldg(w4 + j);
      acc[4 * j + 0] = fmaf(xv, wv.x, acc[4 * j + 0]);
      acc[4 * j + 1] = fmaf(xv, wv.y, acc[4 * j + 1]);
      acc[4 * j + 2] = fmaf(xv, wv.z, acc[4 * j + 2]);
      acc[4 * j + 3] = fmaf(xv, wv.w, acc[4 * j + 3]);
    }
  }
  __syncthreads();                         // xl dead; reuse sm for output staging
#pragma unroll
  for (int j = 0; j < 48; ++j) {
    int o = og * 48 + j;
    float v = acc[j];
    if (o >= 32 && o < 64) {
      v += dt_b[o - 32];
      v = fmaxf(v, 0.f) + log1pf(__expf(-fabsf(v)));   // softplus
    }
    sm[tok * 196 + o] = v;
  }
  __syncthreads();
  float* dst = P + ((size_t)(b * Lt + l0)) * PD;       // 12288 contiguous floats
#pragma unroll
  for (int it = 0; it < 12; ++it) {
    int f = it * 1024 + tid * 4;
    int tk = f / 192;
    float4 v = *(const float4*)(&sm[tk * 196 + (f - tk * 192)]);
    *(float4*)(dst + f) = v;
  }
}

// ---------------- scan phase 1: per-chunk local scan summary (P LDS-staged) ----------------
__global__ __launch_bounds__(256) void k_scan1(const float* __restrict__ P,
    const float* __restrict__ A_log, float* __restrict__ hfin, float* __restrict__ Pc) {
  __shared__ float xl[16][132];
  int bid = blockIdx.x;
  int b = bid & 7; int rest = bid >> 3;
  int c = rest % NC; int rg = rest / NC;      // rg 0..7
  int ws = RFL(threadIdx.x >> 6);
  int r = rg * 4 + ws;
  int n = threadIdx.x & 63;
  float a = -__expf(A_log[r * 64 + n]);
  const float* base = P + ((size_t)(b * Lt + c * CL)) * PD;
  int tl = threadIdx.x >> 4;                  // 0..15
  int colb = (threadIdx.x & 15) * 8;          // 0..120
  float h = 0.f, sdt = 0.f;
  for (int s0 = 0; s0 < CL; s0 += 16) {
    __syncthreads();
    const float4* src = (const float4*)(base + (size_t)(s0 + tl) * PD + colb);
    float4 v0 = src[0], v1 = src[1];
    *(float4*)(&xl[tl][colb]) = v0;
    *(float4*)(&xl[tl][colb + 4]) = v1;
    __syncthreads();
#pragma unroll
    for (int tt = 0; tt < 16; ++tt) {
      float dt = xl[tt][32 + r];
      float u  = xl[tt][r];
      float bt = xl[tt][64 + n];
      h = fmaf(__expf(dt * a), h, (dt * u) * bt);
      sdt += dt;
    }
  }
  int o = ((b * 32 + r) * NC + c) * 64 + n;
  hfin[o] = h;
  Pc[o] = __expf(a * sdt);
}

// ---------------- scan phase 3: inline chunk-prefix + emit states (nontemporal) + y ----------------
__global__ __launch_bounds__(256) void k_scan3(const float* __restrict__ P,
    const float* __restrict__ A_log, const float* __restrict__ hfin,
    const float* __restrict__ Pcp, const float* __restrict__ Dp,
    float* __restrict__ states, float* __restrict__ y) {
  __shared__ float xl[16][196];
  __shared__ __align__(16) float ylds[4][16][68];
  int bid = blockIdx.x;
  int b = bid & 7; int rest = bid >> 3;
  int c = rest % NC; int rg = rest / NC;
  int ws = RFL(threadIdx.x >> 6);
  int r = rg * 4 + ws;
  int n = threadIdx.x & 63;
  float a = -__expf(A_log[r * 64 + n]);
  float Dr = Dp[r];
  const float* base = P + ((size_t)(b * Lt + c * CL)) * PD;
  // inline scan2: prefix over chunks < c
  float h = 0.f;
  {
    int bp = ((b * 32 + r) * NC) * 64 + n;
    for (int cc = 0; cc < c; ++cc)
      h = fmaf(Pcp[bp + cc * 64], h, hfin[bp + cc * 64]);
  }
  float* st = states + ((size_t)(b * Lt + c * CL) * 32 + r) * 64 + n;
  float* yrow = y + (size_t)(b * 32 + r) * Lt + c * CL;
  int tl = threadIdx.x >> 4;
  int colb = (threadIdx.x & 15) * 12;         // 0..180
  for (int s0 = 0; s0 < CL; s0 += 16) {
    __syncthreads();
    const float4* src = (const float4*)(base + (size_t)(s0 + tl) * PD + colb);
    float4 v0 = src[0], v1 = src[1], v2 = src[2];
    *(float4*)(&xl[tl][colb])     = v0;
    *(float4*)(&xl[tl][colb + 4]) = v1;
    *(float4*)(&xl[tl][colb + 8]) = v2;
    __syncthreads();
#pragma unroll
    for (int tt = 0; tt < 16; ++tt) {
      float dt = xl[tt][32 + r];
      float u  = xl[tt][r];
      float bt = xl[tt][64 + n];
      float ct = xl[tt][128 + n];
      h = fmaf(__expf(dt * a), h, (dt * u) * bt);
      __builtin_nontemporal_store(h, st + (size_t)(s0 + tt) * 2048);
      ylds[ws][tt][n] = h * ct;
    }
    if (n < 16) {
      const float4* rp = (const float4*)(&ylds[ws][n][0]);
      float a0 = 0.f, a1 = 0.f, a2 = 0.f, a3 = 0.f;
#pragma unroll
      for (int k = 0; k < 16; ++k) {
        float4 pv = rp[k];
        a0 += pv.x; a1 += pv.y; a2 += pv.z; a3 += pv.w;
      }
      float sum = (a0 + a1) + (a2 + a3);
      float uu = xl[n][r];
      yrow[s0 + n] = sum + Dr * uu;
    }
  }
}

// ---------------- out projection + residual ----------------
__global__ __launch_bounds__(256) void k_outproj(const float* __restrict__ xin,
    const float* __restrict__ y, const float* __restrict__ ow, float* __restrict__ xout) {
  __shared__ float ylds[32 * 64];
  int b = blockIdx.x & 7, tl = blockIdx.x >> 3;
  int l0 = tl * 64;
  int tid = threadIdx.x;
  for (int k = 0; k < 8; ++k) {
    int idx = k * 256 + tid; int r = idx >> 6, li = idx & 63;
    ylds[r * 64 + li] = y[(size_t)(b * 32 + r) * Lt + l0 + li];
  }
  __syncthreads();
  int li = tid & 63, cg = RFL(tid >> 6);
  for (int cc = 0; cc < 16; ++cc) {
    int ci = cg * 16 + cc;
    float acc = xin[(size_t)(b * 64 + ci) * Lt + l0 + li];
    const float4* w4 = (const float4*)(ow + ci * 32);
#pragma unroll
    for (int r4 = 0; r4 < 8; ++r4) {
      float4 wv = __ldg(w4 + r4);
      acc = fmaf(ylds[(r4 * 4 + 0) * 64 + li], wv.x, acc);
      acc = fmaf(ylds[(r4 * 4 + 1) * 64 + li], wv.y, acc);
      acc = fmaf(ylds[(r4 * 4 + 2) * 64 + li], wv.z, acc);
      acc = fmaf(ylds[(r4 * 4 + 3) * 64 + li], wv.w, acc);
    }
    xout[(size_t)(b * 64 + ci) * Lt + l0 + li] = acc;
  }
}

extern "C" void kernel_launch(void* const* d_in, const int* in_sizes, int n_in,
                              void* d_out, int out_size, void* d_ws, size_t ws_size,
                              hipStream_t stream) {
  const float* x      = (const float*)d_in[0];
  const float* stem_w = (const float*)d_in[1];
  const float* stem_g = (const float*)d_in[2];
  const float* stem_b = (const float*)d_in[3];
  const float* stem_m = (const float*)d_in[4];
  const float* stem_v = (const float*)d_in[5];
  const float* in_w   = (const float*)d_in[6];
  const float* dt_w   = (const float*)d_in[7];
  const float* dt_b   = (const float*)d_in[8];
  const float* B_w    = (const float*)d_in[9];
  const float* C_w    = (const float*)d_in[10];
  const float* A_log  = (const float*)d_in[11];
  const float* Dp     = (const float*)d_in[12];
  const float* out_w  = (const float*)d_in[13];
  const float* p4_w   = (const float*)d_in[14];
  const float* p4_g   = (const float*)d_in[15];
  const float* p4_b   = (const float*)d_in[16];
  const float* p4_m   = (const float*)d_in[17];
  const float* p4_v   = (const float*)d_in[18];
  const float* p5_w   = (const float*)d_in[19];
  const float* p5_g   = (const float*)d_in[20];
  const float* p5_b   = (const float*)d_in[21];
  const float* p5_m   = (const float*)d_in[22];
  const float* p5_v   = (const float*)d_in[23];

  float* out = (float*)d_out;
  float* wsf = (float*)d_ws;

  // output regions
  float* p3out = out;                       // 8*64*56*56  = 1605632
  float* p4out = out + 1605632;             // 8*128*28*28 =  802816
  float* p5out = out + 2408448;             // 8*256*14*14 =  401408
  float* stout = out + 2809856;             // 3*8*3136*32*64

  // workspace layout (floats) ~40.7 MB
  float* x0    = wsf;                   // 1605632
  float* x1    = wsf + 1605632;         // 1605632
  float* Pb    = wsf + 3211264;         // 4816896 (8*3136*192)
  float* yb    = wsf + 8028160;         //  802816 (8*32*3136)
  float* hfin  = wsf + 8830976;         //  458752 (8*32*28*64)
  float* Pc    = wsf + 9289728;         //  458752
  float* wT    = wsf + 9748480;         //   36864 (3*64*192)
  float* w3s   = wsf + 9785344;         //   18432 (stem 32*9*64)
  float* w34   = wsf + 9803776;         //   73728 (p4 64*9*128)
  float* w35   = wsf + 9877504;         //  294912 (p5 128*9*256)

  // merged setup: 423936 elems -> 1656 blocks
  k_setup<<<1656, 256, 0, stream>>>(in_w, dt_w, B_w, C_w, stem_w, p4_w, p5_w,
                                    wT, w3s, w34, w35);

  // stem: [8,32,112,112] -> [8,64,56,56]; GWX=8, COG=1 -> 3584 blocks
  k_conv6<32, 64, 112, 112><<<3584, 256, 0, stream>>>(
      x, w3s, stem_g, stem_b, stem_m, stem_v, x0);

  const float* xi = x0;
  for (int i = 0; i < 3; ++i) {
    k_proj<<<392, 256, 0, stream>>>(xi, wT + i * 64 * PD, dt_b + i * 32, Pb);
    k_scan1<<<1792, 256, 0, stream>>>(Pb, A_log + i * 2048, hfin, Pc);
    k_scan3<<<1792, 256, 0, stream>>>(Pb, A_log + i * 2048, hfin, Pc, Dp + i * 32,
                                      stout + (size_t)i * 51380224, yb);
    float* dst = (i == 2) ? p3out : ((i == 0) ? x1 : x0);
    k_outproj<<<392, 256, 0, stream>>>(xi, yb, out_w + i * 2048, dst);
    xi = dst;
  }

  // p4: [8,64,56,56] -> [8,128,28,28]; GWX=4, COG=2 -> 1792 blocks
  k_conv6<64, 128, 56, 56><<<1792, 256, 0, stream>>>(
      p3out, w34, p4_g, p4_b, p4_m, p4_v, p4out);
  // p5: [8,128,28,28] -> [8,256,14,14]; GWX=2, COG=4 -> 896 blocks
  k_conv6<128, 256, 28, 28><<<896, 256, 0, stream>>>(
      p4out, w35, p5_g, p5_b, p5_m, p5_v, p5out);
}